// Round 14
// baseline (183.196 us; speedup 1.0000x reference)
//
#include <hip/hip_runtime.h>
#include <cstdint>
#include <cstddef>

using bf16 = __bf16;
typedef float f32x4 __attribute__((ext_vector_type(4)));
typedef __bf16 bf16x8v __attribute__((ext_vector_type(8)));
typedef __bf16 bf16x4v __attribute__((ext_vector_type(4)));

// Problem constants: B=4, S=2048, D=1024
#define NX   8388608      // 4*2048*1024
#define NW   1048576      // 1024*1024
#define SB   2048
#define DD   1024

__device__ __forceinline__ void gload_lds16(const bf16* g, bf16* l) {
    __builtin_amdgcn_global_load_lds(
        (const __attribute__((address_space(1))) void*)(g),
        (__attribute__((address_space(3))) void*)(l), 16, 0, 0);
}

// ---------------------------------------------------------------------------
// Convert fp32 inputs -> bf16 in workspace; copy biases (fp32) contiguous.
// ---------------------------------------------------------------------------
__global__ __launch_bounds__(256)
void convert_kernel(const float* __restrict__ x1,
                    const float* __restrict__ Wq, const float* __restrict__ Wk,
                    const float* __restrict__ Wv,
                    const float* __restrict__ bq, const float* __restrict__ bk,
                    const float* __restrict__ bv,
                    bf16* __restrict__ xb, bf16* __restrict__ wb,
                    float* __restrict__ biases)
{
    const int NX4 = NX / 4;
    const int NW4 = NW / 4;
    const int NMAT = NX4 + 3 * NW4;
    const int total = NMAT + 768;
    for (int i = blockIdx.x * 256 + threadIdx.x; i < total; i += gridDim.x * 256) {
        if (i < NMAT) {
            const float* src; bf16* dst; int j;
            if (i < NX4) { src = x1; dst = xb; j = i; }
            else {
                int w = (i - NX4) / NW4;
                j = (i - NX4) - w * NW4;
                src = (w == 0) ? Wq : (w == 1) ? Wk : Wv;
                dst = wb + (size_t)w * NW;
            }
            float4 f = ((const float4*)src)[j];
            bf16x4v o;
            o[0] = (bf16)f.x; o[1] = (bf16)f.y; o[2] = (bf16)f.z; o[3] = (bf16)f.w;
            ((bf16x4v*)dst)[j] = o;
        } else {
            int j = i - NMAT;
            const float* src = (j < 256) ? bq : (j < 512) ? bk : bv;
            ((float4*)biases)[j] = ((const float4*)src)[j & 255];
        }
    }
}

// ---------------------------------------------------------------------------
// Persistent fused-QKV GEMM. Grid exactly 8x64 = 512 blocks (full residency,
// 2 blocks/CU, no dispatch rounds). XCD-local mapping (XCD = blockIdx.x per
// the %8 heuristic): b0 = by'>>3, by = (by'&7)*8 + bx' -> each XCD hosts 8
// x-panels (2MB) + 8 weight-panels (2MB) = L2-sized working set.
// Each block runs 3 phases bx = ph*8+b0 (q, k, v weight panels) over the SAME
// A-panel (L1/L2-hot after phase 0). Inner K-loop = round-13 proven ledger:
// vmcnt(8) -> barrier -> 16 ds_read -> lgkmcnt(0)+sched_bar -> barrier ->
// stage(t+2) -> 32 MFMA; tail vmcnt(0).
// Per-phase epilogue through the drained staging LDS:
//   ph<2 (q/k): gather-coalesce -> 8 x 16B global stores per thread
//   ph=2 (v):   transpose -> vT [b][d][s], 128B per thread
// Wide stores keep the next phase's counted vmcnt(8) exact (8 stores + 8
// t0-loads retire together).
// ---------------------------------------------------------------------------
__global__ __launch_bounds__(256)
void qkv_persist(const bf16* __restrict__ A, const bf16* __restrict__ B,
                 bf16* __restrict__ C, bf16* __restrict__ vT,
                 const float* __restrict__ bias)
{
    __shared__ bf16 lds[2][2][8192];   // 64 KiB staging; reused as T
    const int K = 1024;
    const int b0 = blockIdx.y >> 3;
    const int by = ((blockIdx.y & 7) << 3) | blockIdx.x;
    const int m0 = by * 128;

    const int t = threadIdx.x;
    const int lane = t & 63;
    const int wid = t >> 6;
    const int wr = wid >> 1, wc = wid & 1;
    const int rl = lane & 15, lg = lane >> 4;

    bf16* T = &lds[0][0][0];           // 128*132 bf16 = 33.8 KB scratch

    for (int ph = 0; ph < 3; ++ph) {
        const int n0 = (ph * 8 + b0) * 128;

        f32x4 acc[4][4];
        #pragma unroll
        for (int m = 0; m < 4; ++m)
            #pragma unroll
            for (int n = 0; n < 4; ++n) acc[m][n] = (f32x4){0.f, 0.f, 0.f, 0.f};

        auto stage = [&](int b, int k0) {
            #pragma unroll
            for (int l = 0; l < 4; ++l) {
                const int idx = l * 256 + t;
                const int row = idx >> 3;
                const int c   = idx & 7;
                const int gc  = c ^ (row & 7);
                gload_lds16(A + (size_t)(m0 + row) * K + k0 + gc * 8, &lds[b][0][idx * 8]);
                gload_lds16(B + (size_t)(n0 + row) * K + k0 + gc * 8, &lds[b][1][idx * 8]);
            }
        };

        stage(0, 0);
        stage(1, 64);

        for (int tt = 0; tt < 16; ++tt) {
            const int cur = tt & 1;
            if (tt == 15) asm volatile("s_waitcnt vmcnt(0)" ::: "memory");
            else          asm volatile("s_waitcnt vmcnt(8)" ::: "memory");
            __builtin_amdgcn_s_barrier();

            bf16x8v af[2][4], bfr[2][4];
            #pragma unroll
            for (int kk = 0; kk < 2; ++kk) {
                #pragma unroll
                for (int m = 0; m < 4; ++m) {
                    const int row = wr * 64 + m * 16 + rl;
                    const int ch  = (kk * 4 + lg) ^ (row & 7);
                    af[kk][m] = *(const bf16x8v*)&lds[cur][0][row * 64 + ch * 8];
                }
                #pragma unroll
                for (int n = 0; n < 4; ++n) {
                    const int row = wc * 64 + n * 16 + rl;
                    const int ch  = (kk * 4 + lg) ^ (row & 7);
                    bfr[kk][n] = *(const bf16x8v*)&lds[cur][1][row * 64 + ch * 8];
                }
            }
            asm volatile("s_waitcnt lgkmcnt(0)" ::: "memory");
            __builtin_amdgcn_sched_barrier(0);
            __builtin_amdgcn_s_barrier();

            if (tt + 2 < 16) stage(cur, (tt + 2) * 64);

            #pragma unroll
            for (int kk = 0; kk < 2; ++kk)
                #pragma unroll
                for (int m = 0; m < 4; ++m)
                    #pragma unroll
                    for (int n = 0; n < 4; ++n)
                        acc[m][n] = __builtin_amdgcn_mfma_f32_16x16x32_bf16(
                            af[kk][m], bfr[kk][n], acc[m][n], 0, 0, 0);
        }

        // ---- epilogue (pipeline fully drained; LDS free) ----
        const int cif = rl;
        const int rif = lg << 2;

        if (ph < 2) {
            // gather-coalesce: T[sl][dl], row stride 132 bf16
            #pragma unroll
            for (int m = 0; m < 4; ++m) {
                const int sl = wr * 64 + m * 16 + rif;
                #pragma unroll
                for (int n = 0; n < 4; ++n) {
                    const int dl = wc * 64 + n * 16 + cif;
                    const float bbv = bias[n0 + dl];
                    #pragma unroll
                    for (int r = 0; r < 4; ++r)
                        T[(sl + r) * 132 + dl] = (bf16)(acc[m][n][r] + bbv);
                }
            }
            __syncthreads();
            // thread -> (s = t>>1, half = (t&1)*64): 64 contig bf16 = 128B
            const int s  = t >> 1;
            const int hh = (t & 1) << 6;
            bf16* dst = (ph == 0 ? C : C + NX)
                        + (size_t)(m0 + s) * 1024 + (n0 & 1023) + hh;
            const uint2* srcp = (const uint2*)&T[s * 132 + hh];
            #pragma unroll
            for (int j = 0; j < 8; ++j) {
                uint2 a = srcp[2 * j], b2 = srcp[2 * j + 1];
                ((uint4*)dst)[j] = (uint4){a.x, a.y, b2.x, b2.y};
            }
        } else {
            // transpose: T[dl][sl], row stride 132 bf16 -> vT [b][d][s]
            #pragma unroll
            for (int m = 0; m < 4; ++m) {
                const int sl = wr * 64 + m * 16 + rif;
                #pragma unroll
                for (int n = 0; n < 4; ++n) {
                    const int dl = wc * 64 + n * 16 + cif;
                    const float bbv = bias[n0 + dl];
                    bf16x4v pk;
                    #pragma unroll
                    for (int r = 0; r < 4; ++r) pk[r] = (bf16)(acc[m][n][r] + bbv);
                    *(bf16x4v*)&T[dl * 132 + sl] = pk;
                }
            }
            __syncthreads();
            const int d  = t >> 1;
            const int sh = (t & 1) << 6;
            const int batch = m0 >> 11;
            const int dg = n0 - 2048 + d;
            const int sg = (m0 & 2047) + sh;
            uint4* dst = (uint4*)&vT[((size_t)batch << 21) + ((size_t)dg << 11) + sg];
            const uint2* srcp = (const uint2*)&T[d * 132 + sh];
            #pragma unroll
            for (int j = 0; j < 8; ++j) {
                uint2 a = srcp[2 * j], b2 = srcp[2 * j + 1];
                dst[j] = (uint4){a.x, a.y, b2.x, b2.y};
            }
        }
        __syncthreads();   // T reads retired before next phase stages
    }
}

// ---------------------------------------------------------------------------
// Double-buffered counted-vmcnt 128x128 GEMM (round-11/13 champion).
// V=1: scores: P~ = exp2(acc*scale*log2e - 6*log2e) bf16 + partial row-sums
//      pRow[row*32 + bx*2 + wc] (deterministic, no atomics).
// V=2: PV: f32 out scaled by 1/rowsum (reduced from pRow at block entry).
// ---------------------------------------------------------------------------
template<int V, typename OutT>
__global__ __launch_bounds__(256)
void gemm_bt(const bf16* __restrict__ A, const bf16* __restrict__ B,
             OutT* __restrict__ C, bf16* __restrict__ vT,
             const float* __restrict__ bias, float* __restrict__ pRow,
             int N, int K, int GRP,
             long sAz, long sBz, long sCz, float scale)
{
    __shared__ bf16 lds[2][2][8192];   // [buf][A|B][128*64] = 64 KiB
    __shared__ float inv[128];         // V==2 only
    const int z = blockIdx.z;
    A += (size_t)z * sAz;
    B += (size_t)z * sBz;
    C += (size_t)z * sCz;
    pRow += (size_t)z * (SB * 32);

    // T1: XCD-aware bijective swizzle of the flattened 2D grid
    const int gx = gridDim.x;
    const int gy = gridDim.y;
    const int nwg = gx * gy;
    const int orig = (int)blockIdx.y * gx + (int)blockIdx.x;
    const int q8 = nwg >> 3;
    const int tile = (orig & 7) * q8 + (orig >> 3);
    const int gsz = GRP * gy;
    const int bxg = tile / gsz;
    const int rem = tile - bxg * gsz;
    const int by  = rem / GRP;
    const int bx  = bxg * GRP + (rem - (rem / GRP) * GRP);

    const int n0 = bx * 128;
    const int m0 = by * 128;
    const int t = threadIdx.x;
    const int lane = t & 63;
    const int wid = t >> 6;
    const int wr = wid >> 1, wc = wid & 1;
    const int rl = lane & 15, lg = lane >> 4;

    if constexpr (V == 2) {
        if (t < 128) {
            const float4* pr = (const float4*)&pRow[(size_t)(m0 + t) * 32];
            float s = 0.f;
            #pragma unroll
            for (int j = 0; j < 8; ++j) {
                float4 f = pr[j];
                s += f.x + f.y + f.z + f.w;
            }
            inv[t] = 1.0f / s;
        }
        __syncthreads();
    }

    f32x4 acc[4][4];
    #pragma unroll
    for (int m = 0; m < 4; ++m)
        #pragma unroll
        for (int n = 0; n < 4; ++n) acc[m][n] = (f32x4){0.f, 0.f, 0.f, 0.f};

    auto stage = [&](int b, int k0) {
        #pragma unroll
        for (int l = 0; l < 4; ++l) {
            const int idx = l * 256 + t;
            const int row = idx >> 3;
            const int c   = idx & 7;
            const int gc  = c ^ (row & 7);
            gload_lds16(A + (size_t)(m0 + row) * K + k0 + gc * 8, &lds[b][0][idx * 8]);
            gload_lds16(B + (size_t)(n0 + row) * K + k0 + gc * 8, &lds[b][1][idx * 8]);
        }
    };

    const int NT = K >> 6;

    stage(0, 0);
    stage(1, 64);

    for (int tt = 0; tt < NT; ++tt) {
        const int cur = tt & 1;
        if (tt == NT - 1) asm volatile("s_waitcnt vmcnt(0)" ::: "memory");
        else              asm volatile("s_waitcnt vmcnt(8)" ::: "memory");
        __builtin_amdgcn_s_barrier();

        bf16x8v af[2][4], bfr[2][4];
        #pragma unroll
        for (int kk = 0; kk < 2; ++kk) {
            #pragma unroll
            for (int m = 0; m < 4; ++m) {
                const int row = wr * 64 + m * 16 + rl;
                const int ch  = (kk * 4 + lg) ^ (row & 7);
                af[kk][m] = *(const bf16x8v*)&lds[cur][0][row * 64 + ch * 8];
            }
            #pragma unroll
            for (int n = 0; n < 4; ++n) {
                const int row = wc * 64 + n * 16 + rl;
                const int ch  = (kk * 4 + lg) ^ (row & 7);
                bfr[kk][n] = *(const bf16x8v*)&lds[cur][1][row * 64 + ch * 8];
            }
        }
        asm volatile("s_waitcnt lgkmcnt(0)" ::: "memory");
        __builtin_amdgcn_sched_barrier(0);
        __builtin_amdgcn_s_barrier();

        if (tt + 2 < NT) stage(cur, (tt + 2) * 64);

        #pragma unroll
        for (int kk = 0; kk < 2; ++kk)
            #pragma unroll
            for (int m = 0; m < 4; ++m)
                #pragma unroll
                for (int n = 0; n < 4; ++n)
                    acc[m][n] = __builtin_amdgcn_mfma_f32_16x16x32_bf16(
                        af[kk][m], bfr[kk][n], acc[m][n], 0, 0, 0);
    }

    const int cif = rl;
    const int rif = lg << 2;

    if constexpr (V == 1) {
        const float sc2 = scale * 1.4426950408889634f;
        const float sh2 = -8.656170245333781f;   // -6 * log2(e)
        float rs[4][4];
        #pragma unroll
        for (int m = 0; m < 4; ++m)
            #pragma unroll
            for (int r = 0; r < 4; ++r) rs[m][r] = 0.f;

        #pragma unroll
        for (int m = 0; m < 4; ++m) {
            const int gm = m0 + wr * 64 + m * 16 + rif;
            #pragma unroll
            for (int n = 0; n < 4; ++n) {
                const int col = n0 + wc * 64 + n * 16 + cif;
                #pragma unroll
                for (int r = 0; r < 4; ++r) {
                    const float e = exp2f(fmaf(acc[m][n][r], sc2, sh2));
                    rs[m][r] += e;
                    C[(size_t)(gm + r) * N + col] = (OutT)e;
                }
            }
        }
        #pragma unroll
        for (int m = 0; m < 4; ++m)
            #pragma unroll
            for (int r = 0; r < 4; ++r) {
                #pragma unroll
                for (int msk = 1; msk < 16; msk <<= 1)
                    rs[m][r] += __shfl_xor(rs[m][r], msk);
            }
        if ((lane & 15) == 0) {
            const int slot = bx * 2 + wc;
            #pragma unroll
            for (int m = 0; m < 4; ++m) {
                const int gm = m0 + wr * 64 + m * 16 + rif;
                #pragma unroll
                for (int r = 0; r < 4; ++r)
                    pRow[(size_t)(gm + r) * 32 + slot] = rs[m][r];
            }
        }
    } else {  // V == 2: normalize by row sum
        #pragma unroll
        for (int m = 0; m < 4; ++m) {
            const int gm = m0 + wr * 64 + m * 16 + rif;
            const int rloc = wr * 64 + m * 16 + rif;
            #pragma unroll
            for (int n = 0; n < 4; ++n) {
                const int col = n0 + wc * 64 + n * 16 + cif;
                #pragma unroll
                for (int r = 0; r < 4; ++r)
                    C[(size_t)(gm + r) * N + col] = (OutT)(acc[m][n][r] * inv[rloc + r]);
            }
        }
    }
}

// ---------------------------------------------------------------------------
extern "C" void kernel_launch(void* const* d_in, const int* in_sizes, int n_in,
                              void* d_out, int out_size, void* d_ws, size_t ws_size,
                              hipStream_t stream)
{
    const float* x1 = (const float*)d_in[0];
    const float* Wq = (const float*)d_in[1];
    const float* bq = (const float*)d_in[2];
    const float* Wk = (const float*)d_in[3];
    const float* bk = (const float*)d_in[4];
    const float* Wv = (const float*)d_in[5];
    const float* bv = (const float*)d_in[6];
    float* out = (float*)d_out;

    // workspace layout (bf16 elements unless noted)
    bf16* xb     = (bf16*)d_ws;             // x bf16; reused as pRow after QKV
    bf16* wb     = xb + NX;                 // 3*1048576 (Wq,Wk,Wv rows x 1024)
    bf16* qkb    = wb + 3 * NW;             // 2*8388608 (q then k)
    bf16* vTb    = qkb + 2 * (size_t)NX;    // 8388608 (V^T per batch [D][S])
    bf16* scores = vTb + NX;                // 4*2048*2048 (P~)
    float* biases = (float*)(scores + 4 * (size_t)SB * SB); // 3072 f32
    float* partial = (float*)xb;            // [4][2048][32] f32 (xb dead post-QKV)

    // 1. convert inputs to bf16
    convert_kernel<<<dim3(2048), dim3(256), 0, stream>>>(
        x1, Wq, Wk, Wv, bq, bk, bv, xb, wb, biases);

    // 2. persistent fused QKV: 512 blocks, 3 weight-panel phases each
    qkv_persist<<<dim3(8, 64), dim3(256), 0, stream>>>(
        xb, wb, qkb, vTb, biases);

    // 3. P~ = exp(QK^T/32 - 6) per batch + partial row sums: M=N=2048, K=1024
    gemm_bt<1, bf16><<<dim3(16, 16, 4), dim3(256), 0, stream>>>(
        qkb, qkb + NX, scores, nullptr, nullptr, partial, SB, DD, 16,
        (long)(SB * DD), (long)(SB * DD), (long)(SB * SB), 1.0f / 32.0f);

    // 4. out = (P~ V) / rowsum per batch: M=2048, N=1024, K=2048, f32 out
    gemm_bt<2, float><<<dim3(8, 16, 4), dim3(256), 0, stream>>>(
        scores, vTb, out, nullptr, nullptr, partial, DD, SB, 8,
        (long)(SB * SB), (long)(SB * DD), (long)(SB * DD), 1.0f);
}

// Round 15
// 169.283 us; speedup vs baseline: 1.0822x; 1.0822x over previous
//
#include <hip/hip_runtime.h>
#include <cstdint>
#include <cstddef>

using bf16 = __bf16;
typedef float f32x4 __attribute__((ext_vector_type(4)));
typedef __bf16 bf16x8v __attribute__((ext_vector_type(8)));
typedef __bf16 bf16x4v __attribute__((ext_vector_type(4)));

// Problem constants: B=4, S=2048, D=1024
#define NX   8388608      // 4*2048*1024
#define NW   1048576      // 1024*1024
#define SB   2048
#define DD   1024

__device__ __forceinline__ void gload_lds16(const bf16* g, bf16* l) {
    __builtin_amdgcn_global_load_lds(
        (const __attribute__((address_space(1))) void*)(g),
        (__attribute__((address_space(3))) void*)(l), 16, 0, 0);
}

// ---------------------------------------------------------------------------
// Convert fp32 inputs -> bf16 in workspace; copy biases (fp32) contiguous.
// ---------------------------------------------------------------------------
__global__ __launch_bounds__(256)
void convert_kernel(const float* __restrict__ x1,
                    const float* __restrict__ Wq, const float* __restrict__ Wk,
                    const float* __restrict__ Wv,
                    const float* __restrict__ bq, const float* __restrict__ bk,
                    const float* __restrict__ bv,
                    bf16* __restrict__ xb, bf16* __restrict__ wb,
                    float* __restrict__ biases)
{
    const int NX4 = NX / 4;
    const int NW4 = NW / 4;
    const int NMAT = NX4 + 3 * NW4;
    const int total = NMAT + 768;
    for (int i = blockIdx.x * 256 + threadIdx.x; i < total; i += gridDim.x * 256) {
        if (i < NMAT) {
            const float* src; bf16* dst; int j;
            if (i < NX4) { src = x1; dst = xb; j = i; }
            else {
                int w = (i - NX4) / NW4;
                j = (i - NX4) - w * NW4;
                src = (w == 0) ? Wq : (w == 1) ? Wk : Wv;
                dst = wb + (size_t)w * NW;
            }
            float4 f = ((const float4*)src)[j];
            bf16x4v o;
            o[0] = (bf16)f.x; o[1] = (bf16)f.y; o[2] = (bf16)f.z; o[3] = (bf16)f.w;
            ((bf16x4v*)dst)[j] = o;
        } else {
            int j = i - NMAT;
            const float* src = (j < 256) ? bq : (j < 512) ? bk : bv;
            ((float4*)biases)[j] = ((const float4*)src)[j & 255];
        }
    }
}

// ---------------------------------------------------------------------------
// Double-buffered counted-vmcnt 128x128 GEMM (round-13 champion structure).
// Per K-tile: vmcnt(8) -> barrier -> 16 ds_read -> lgkmcnt(0)+sched_bar ->
// barrier -> stage(t+2) into freed buffer (loads cross barriers) -> 32 MFMA.
// Tail: vmcnt(0) at t=NT-1.
// C[m][n] = scale * sum_k A[m][k]*B[n][k] (+ epilogue routing)
// A: M x K, B: N x K row-major bf16. 4 waves (2x2 of 64x64), 16x16x32 MFMA.
// Conflict-free XOR swizzle (chunk ^= row&7); T1 XCD block swizzle + GRP
// bx-grouping (L2 working-set control; GRP==gridDim.x -> plain order).
// ALL bf16 epilogues coalesce through the drained staging LDS (T, stride 132)
// into 8 x 16B full-sector stores per thread (round-14-validated paths):
// V=0: QKV. q/k blocks gather T[sl][dl]; v blocks (n0>=2048) transpose
//      T[dl][sl] -> vT [b][d][s].
// V=1: scores: P~ = exp2(acc*scale*log2e - 6*log2e); register rowsum ->
//      pRow[row*32 + bx*2 + wc]; P~ tile coalesced through T.
// V=2: PV: f32 out scaled by 1/rowsum (already full-sector 64B runs; direct).
// ---------------------------------------------------------------------------
template<int V, typename OutT>
__global__ __launch_bounds__(256)
void gemm_bt(const bf16* __restrict__ A, const bf16* __restrict__ B,
             OutT* __restrict__ C, bf16* __restrict__ vT,
             const float* __restrict__ bias, float* __restrict__ pRow,
             int N, int K, int GRP,
             long sAz, long sBz, long sCz, float scale)
{
    __shared__ bf16 lds[2][2][8192];   // [buf][A|B][128*64] = 64 KiB
    __shared__ float inv[128];         // V==2 only
    const int z = blockIdx.z;
    A += (size_t)z * sAz;
    B += (size_t)z * sBz;
    C += (size_t)z * sCz;
    if constexpr (V == 1 || V == 2) pRow += (size_t)z * (SB * 32);

    // T1: XCD-aware bijective swizzle of the flattened 2D grid
    const int gx = gridDim.x;
    const int gy = gridDim.y;
    const int nwg = gx * gy;
    const int orig = (int)blockIdx.y * gx + (int)blockIdx.x;
    const int q8 = nwg >> 3;
    const int tile = (orig & 7) * q8 + (orig >> 3);
    // bx-grouped ordering: (bx-group, by, bx-in-group); GRP==gx -> plain
    const int gsz = GRP * gy;
    const int bxg = tile / gsz;
    const int rem = tile - bxg * gsz;
    const int by  = rem / GRP;
    const int bx  = bxg * GRP + (rem - (rem / GRP) * GRP);

    const int n0 = bx * 128;
    const int m0 = by * 128;
    const int t = threadIdx.x;
    const int lane = t & 63;
    const int wid = t >> 6;
    const int wr = wid >> 1, wc = wid & 1;
    const int rl = lane & 15, lg = lane >> 4;

    if constexpr (V == 2) {
        if (t < 128) {
            const float4* pr = (const float4*)&pRow[(size_t)(m0 + t) * 32];
            float s = 0.f;
            #pragma unroll
            for (int j = 0; j < 8; ++j) {
                float4 f = pr[j];
                s += f.x + f.y + f.z + f.w;
            }
            inv[t] = 1.0f / s;
        }
        __syncthreads();
    }

    f32x4 acc[4][4];
    #pragma unroll
    for (int m = 0; m < 4; ++m)
        #pragma unroll
        for (int n = 0; n < 4; ++n) acc[m][n] = (f32x4){0.f, 0.f, 0.f, 0.f};

    // stage one full K-tile (A+B, 8 gload_lds per thread, FIFO order fixed)
    auto stage = [&](int b, int k0) {
        #pragma unroll
        for (int l = 0; l < 4; ++l) {
            const int idx = l * 256 + t;
            const int row = idx >> 3;
            const int c   = idx & 7;
            const int gc  = c ^ (row & 7);   // inverse-swizzled source chunk
            gload_lds16(A + (size_t)(m0 + row) * K + k0 + gc * 8, &lds[b][0][idx * 8]);
            gload_lds16(B + (size_t)(n0 + row) * K + k0 + gc * 8, &lds[b][1][idx * 8]);
        }
    };

    const int NT = K >> 6;

    // prologue: tiles 0 and 1 in flight (16 loads/thread outstanding)
    stage(0, 0);
    stage(1, 64);

    for (int tt = 0; tt < NT; ++tt) {
        const int cur = tt & 1;
        // counted wait: tile tt resident (its 8 loads are the oldest)
        if (tt == NT - 1) asm volatile("s_waitcnt vmcnt(0)" ::: "memory");
        else              asm volatile("s_waitcnt vmcnt(8)" ::: "memory");
        __builtin_amdgcn_s_barrier();

        // read ALL fragments for both kk halves
        bf16x8v af[2][4], bfr[2][4];
        #pragma unroll
        for (int kk = 0; kk < 2; ++kk) {
            #pragma unroll
            for (int m = 0; m < 4; ++m) {
                const int row = wr * 64 + m * 16 + rl;
                const int ch  = (kk * 4 + lg) ^ (row & 7);
                af[kk][m] = *(const bf16x8v*)&lds[cur][0][row * 64 + ch * 8];
            }
            #pragma unroll
            for (int n = 0; n < 4; ++n) {
                const int row = wc * 64 + n * 16 + rl;
                const int ch  = (kk * 4 + lg) ^ (row & 7);
                bfr[kk][n] = *(const bf16x8v*)&lds[cur][1][row * 64 + ch * 8];
            }
        }
        asm volatile("s_waitcnt lgkmcnt(0)" ::: "memory");
        __builtin_amdgcn_sched_barrier(0);
        __builtin_amdgcn_s_barrier();   // all waves' reads of buf[cur] retired

        // refill the just-freed buffer; loads stay in flight across barriers
        if (tt + 2 < NT) stage(cur, (tt + 2) * 64);

        #pragma unroll
        for (int kk = 0; kk < 2; ++kk)
            #pragma unroll
            for (int m = 0; m < 4; ++m)
                #pragma unroll
                for (int n = 0; n < 4; ++n)
                    acc[m][n] = __builtin_amdgcn_mfma_f32_16x16x32_bf16(
                        af[kk][m], bfr[kk][n], acc[m][n], 0, 0, 0);
    }

    // epilogue: C/D map col=lane&15, row=(lane>>4)*4+reg (m89-verified)
    // staging LDS is fully drained after the loop's final barrier -> reuse as T
    const int cif = rl;
    const int rif = lg << 2;
    bf16* T = &lds[0][0][0];   // 128*132 bf16 = 33.8 KB scratch

    if constexpr (V == 1) {
        const float sc2 = scale * 1.4426950408889634f;
        const float sh2 = -8.656170245333781f;   // -6 * log2(e)
        float rs[4][4];   // [m][r] partial row sums over this lane's cols
        #pragma unroll
        for (int m = 0; m < 4; ++m)
            #pragma unroll
            for (int r = 0; r < 4; ++r) rs[m][r] = 0.f;

        // exp into T (gather layout T[sl][dl]) + register rowsum
        #pragma unroll
        for (int m = 0; m < 4; ++m) {
            const int sl = wr * 64 + m * 16 + rif;
            #pragma unroll
            for (int n = 0; n < 4; ++n) {
                const int dl = wc * 64 + n * 16 + cif;
                #pragma unroll
                for (int r = 0; r < 4; ++r) {
                    const float e = exp2f(fmaf(acc[m][n][r], sc2, sh2));
                    rs[m][r] += e;
                    T[(sl + r) * 132 + dl] = (bf16)e;
                }
            }
        }
        // reduce over the 16 rl-lanes (same rows, different cols)
        #pragma unroll
        for (int m = 0; m < 4; ++m)
            #pragma unroll
            for (int r = 0; r < 4; ++r) {
                #pragma unroll
                for (int msk = 1; msk < 16; msk <<= 1)
                    rs[m][r] += __shfl_xor(rs[m][r], msk);
            }
        if ((lane & 15) == 0) {
            const int slot = bx * 2 + wc;
            #pragma unroll
            for (int m = 0; m < 4; ++m) {
                const int gm = m0 + wr * 64 + m * 16 + rif;
                #pragma unroll
                for (int r = 0; r < 4; ++r)
                    pRow[(size_t)(gm + r) * 32 + slot] = rs[m][r];
            }
        }
        __syncthreads();
        // coalesced store: thread -> (s = t>>1, half = (t&1)*64), 128B each
        const int s  = t >> 1;
        const int hh = (t & 1) << 6;
        bf16* dst = (bf16*)C + (size_t)(m0 + s) * N + n0 + hh;
        const uint2* srcp = (const uint2*)&T[s * 132 + hh];
        #pragma unroll
        for (int j = 0; j < 8; ++j) {
            uint2 a = srcp[2 * j], b2 = srcp[2 * j + 1];
            ((uint4*)dst)[j] = (uint4){a.x, a.y, b2.x, b2.y};
        }
    } else if constexpr (V == 0) {
        if (n0 >= 2048) {
            // v-region block: transpose T[dl][sl] -> vT coalesced (round-13)
            #pragma unroll
            for (int m = 0; m < 4; ++m) {
                const int sl = wr * 64 + m * 16 + rif;   // s_local (r contiguous)
                #pragma unroll
                for (int n = 0; n < 4; ++n) {
                    const int dl = wc * 64 + n * 16 + cif;  // d_local
                    const float bb = bias[n0 + dl];
                    bf16x4v pk;
                    #pragma unroll
                    for (int r = 0; r < 4; ++r) pk[r] = (bf16)(acc[m][n][r] + bb);
                    *(bf16x4v*)&T[dl * 132 + sl] = pk;
                }
            }
            __syncthreads();
            const int d  = t >> 1;
            const int sh = (t & 1) << 6;
            const int batch = m0 >> 11;
            const int dg = n0 - 2048 + d;
            const int sg = (m0 & 2047) + sh;
            uint4* dst = (uint4*)&vT[((size_t)batch << 21) + ((size_t)dg << 11) + sg];
            const uint2* srcp = (const uint2*)&T[d * 132 + sh];
            #pragma unroll
            for (int j = 0; j < 8; ++j) {
                uint2 a = srcp[2 * j], b2 = srcp[2 * j + 1];
                dst[j] = (uint4){a.x, a.y, b2.x, b2.y};
            }
        } else {
            // q/k block: gather T[sl][dl] -> coalesced store (round-14 path)
            #pragma unroll
            for (int m = 0; m < 4; ++m) {
                const int sl = wr * 64 + m * 16 + rif;
                #pragma unroll
                for (int n = 0; n < 4; ++n) {
                    const int dl = wc * 64 + n * 16 + cif;
                    const float bb = bias[n0 + dl];
                    #pragma unroll
                    for (int r = 0; r < 4; ++r)
                        T[(sl + r) * 132 + dl] = (bf16)(acc[m][n][r] + bb);
                }
            }
            __syncthreads();
            const int s  = t >> 1;
            const int hh = (t & 1) << 6;
            bf16* dst = (n0 < 1024 ? (bf16*)C : (bf16*)C + NX)
                        + (size_t)(m0 + s) * 1024 + (n0 & 1023) + hh;
            const uint2* srcp = (const uint2*)&T[s * 132 + hh];
            #pragma unroll
            for (int j = 0; j < 8; ++j) {
                uint2 a = srcp[2 * j], b2 = srcp[2 * j + 1];
                ((uint4*)dst)[j] = (uint4){a.x, a.y, b2.x, b2.y};
            }
        }
    } else {  // V == 2: normalize by row sum; f32 stores are full 64B runs
        #pragma unroll
        for (int m = 0; m < 4; ++m) {
            const int gm = m0 + wr * 64 + m * 16 + rif;
            const int rloc = wr * 64 + m * 16 + rif;
            #pragma unroll
            for (int n = 0; n < 4; ++n) {
                const int col = n0 + wc * 64 + n * 16 + cif;
                #pragma unroll
                for (int r = 0; r < 4; ++r)
                    C[(size_t)(gm + r) * N + col] = (OutT)(acc[m][n][r] * inv[rloc + r]);
            }
        }
    }
}

// ---------------------------------------------------------------------------
extern "C" void kernel_launch(void* const* d_in, const int* in_sizes, int n_in,
                              void* d_out, int out_size, void* d_ws, size_t ws_size,
                              hipStream_t stream)
{
    const float* x1 = (const float*)d_in[0];
    const float* Wq = (const float*)d_in[1];
    const float* bq = (const float*)d_in[2];
    const float* Wk = (const float*)d_in[3];
    const float* bk = (const float*)d_in[4];
    const float* Wv = (const float*)d_in[5];
    const float* bv = (const float*)d_in[6];
    float* out = (float*)d_out;

    // workspace layout (bf16 elements unless noted)
    bf16* xb     = (bf16*)d_ws;             // x bf16; reused as pRow after QKV
    bf16* wb     = xb + NX;                 // 3*1048576 (Wq,Wk,Wv rows x 1024)
    bf16* qkb    = wb + 3 * NW;             // 2*8388608 (q then k)
    bf16* vTb    = qkb + 2 * (size_t)NX;    // 8388608 (V^T per batch [D][S])
    bf16* scores = vTb + NX;                // 4*2048*2048 (P~)
    float* biases = (float*)(scores + 4 * (size_t)SB * SB); // 3072 f32
    float* partial = (float*)xb;            // [4][2048][32] f32 (xb dead post-QKV)

    // 1. convert inputs to bf16
    convert_kernel<<<dim3(2048), dim3(256), 0, stream>>>(
        x1, Wq, Wk, Wv, bq, bk, bv, xb, wb, biases);

    // 2. fused QKV projection: M=8192, N=3072 (q|k|vT), K=1024; GRP=8 keeps
    //    per-XCD working set inside L2
    gemm_bt<0, bf16><<<dim3(24, 64, 1), dim3(256), 0, stream>>>(
        xb, wb, qkb, vTb, biases, nullptr, 1024, 1024, 8, 0L, 0L, 0L, 1.0f);

    // 3. P~ = exp(QK^T/32 - 6) per batch + partial row sums: M=N=2048, K=1024
    gemm_bt<1, bf16><<<dim3(16, 16, 4), dim3(256), 0, stream>>>(
        qkb, qkb + NX, scores, nullptr, nullptr, partial, SB, DD, 16,
        (long)(SB * DD), (long)(SB * DD), (long)(SB * SB), 1.0f / 32.0f);

    // 4. out = (P~ V) / rowsum per batch: M=2048, N=1024, K=2048, f32 out
    gemm_bt<2, float><<<dim3(8, 16, 4), dim3(256), 0, stream>>>(
        scores, vTb, out, nullptr, nullptr, partial, DD, SB, 8,
        (long)(SB * SB), (long)(SB * DD), (long)(SB * DD), 1.0f);
}

// Round 16
// 161.317 us; speedup vs baseline: 1.1356x; 1.0494x over previous
//
#include <hip/hip_runtime.h>
#include <cstdint>
#include <cstddef>

using bf16 = __bf16;
typedef float f32x4 __attribute__((ext_vector_type(4)));
typedef __bf16 bf16x8v __attribute__((ext_vector_type(8)));
typedef __bf16 bf16x4v __attribute__((ext_vector_type(4)));

// Problem constants: B=4, S=2048, D=1024
#define NX   8388608      // 4*2048*1024
#define NW   1048576      // 1024*1024
#define SB   2048
#define DD   1024

__device__ __forceinline__ void gload_lds16(const bf16* g, bf16* l) {
    __builtin_amdgcn_global_load_lds(
        (const __attribute__((address_space(1))) void*)(g),
        (__attribute__((address_space(3))) void*)(l), 16, 0, 0);
}

// ---------------------------------------------------------------------------
// Convert fp32 inputs -> bf16 in workspace; copy biases (fp32) contiguous.
// ---------------------------------------------------------------------------
__global__ __launch_bounds__(256)
void convert_kernel(const float* __restrict__ x1,
                    const float* __restrict__ Wq, const float* __restrict__ Wk,
                    const float* __restrict__ Wv,
                    const float* __restrict__ bq, const float* __restrict__ bk,
                    const float* __restrict__ bv,
                    bf16* __restrict__ xb, bf16* __restrict__ wb,
                    float* __restrict__ biases)
{
    const int NX4 = NX / 4;
    const int NW4 = NW / 4;
    const int NMAT = NX4 + 3 * NW4;
    const int total = NMAT + 768;
    for (int i = blockIdx.x * 256 + threadIdx.x; i < total; i += gridDim.x * 256) {
        if (i < NMAT) {
            const float* src; bf16* dst; int j;
            if (i < NX4) { src = x1; dst = xb; j = i; }
            else {
                int w = (i - NX4) / NW4;
                j = (i - NX4) - w * NW4;
                src = (w == 0) ? Wq : (w == 1) ? Wk : Wv;
                dst = wb + (size_t)w * NW;
            }
            float4 f = ((const float4*)src)[j];
            bf16x4v o;
            o[0] = (bf16)f.x; o[1] = (bf16)f.y; o[2] = (bf16)f.z; o[3] = (bf16)f.w;
            ((bf16x4v*)dst)[j] = o;
        } else {
            int j = i - NMAT;
            const float* src = (j < 256) ? bq : (j < 512) ? bk : bv;
            ((float4*)biases)[j] = ((const float4*)src)[j & 255];
        }
    }
}

// ---------------------------------------------------------------------------
// Double-buffered counted-vmcnt 128x128 GEMM (round-13 champion structure).
// Per K-tile: vmcnt(8) -> barrier -> 16 ds_read -> lgkmcnt(0)+sched_bar ->
// barrier -> stage(t+2) into freed buffer (loads cross barriers) -> 32 MFMA.
// Tail: vmcnt(0) at t=NT-1.
// C[m][n] = scale * sum_k A[m][k]*B[n][k] (+ epilogue routing)
// A: M x K, B: N x K row-major bf16. 4 waves (2x2 of 64x64), 16x16x32 MFMA.
// Conflict-free XOR swizzle (chunk ^= row&7); T1 XCD block swizzle + GRP
// bx-grouping (L2 working-set control; GRP==gridDim.x -> plain order).
// Epilogue policy (round-15 lesson): LDS-coalesce ONLY scatter/scalar store
// patterns (V0's q/k 2B-scalar and v 8B@4KB-stride); direct-store wave-
// interleaved runs that already fill sectors (V1 scores, V2 f32).
// V=0: QKV. q/k blocks gather T[sl][dl] -> 8x16B stores; v blocks (n0>=2048)
//      transpose T[dl][sl] -> vT [b][d][s], 128B/thread.
// V=1: scores: P~ = exp2(acc*scale*log2e - 6*log2e) bf16, DIRECT stores +
//      register rowsum -> pRow[row*32 + bx*2 + wc] (deterministic).
// V=2: PV: f32 out scaled by 1/rowsum (reduced from pRow at block entry).
// ---------------------------------------------------------------------------
template<int V, typename OutT>
__global__ __launch_bounds__(256)
void gemm_bt(const bf16* __restrict__ A, const bf16* __restrict__ B,
             OutT* __restrict__ C, bf16* __restrict__ vT,
             const float* __restrict__ bias, float* __restrict__ pRow,
             int N, int K, int GRP,
             long sAz, long sBz, long sCz, float scale)
{
    __shared__ bf16 lds[2][2][8192];   // [buf][A|B][128*64] = 64 KiB
    __shared__ float inv[128];         // V==2 only
    const int z = blockIdx.z;
    A += (size_t)z * sAz;
    B += (size_t)z * sBz;
    C += (size_t)z * sCz;
    if constexpr (V == 1 || V == 2) pRow += (size_t)z * (SB * 32);

    // T1: XCD-aware bijective swizzle of the flattened 2D grid
    const int gx = gridDim.x;
    const int gy = gridDim.y;
    const int nwg = gx * gy;
    const int orig = (int)blockIdx.y * gx + (int)blockIdx.x;
    const int q8 = nwg >> 3;
    const int tile = (orig & 7) * q8 + (orig >> 3);
    // bx-grouped ordering: (bx-group, by, bx-in-group); GRP==gx -> plain
    const int gsz = GRP * gy;
    const int bxg = tile / gsz;
    const int rem = tile - bxg * gsz;
    const int by  = rem / GRP;
    const int bx  = bxg * GRP + (rem - (rem / GRP) * GRP);

    const int n0 = bx * 128;
    const int m0 = by * 128;
    const int t = threadIdx.x;
    const int lane = t & 63;
    const int wid = t >> 6;
    const int wr = wid >> 1, wc = wid & 1;
    const int rl = lane & 15, lg = lane >> 4;

    if constexpr (V == 2) {
        if (t < 128) {
            const float4* pr = (const float4*)&pRow[(size_t)(m0 + t) * 32];
            float s = 0.f;
            #pragma unroll
            for (int j = 0; j < 8; ++j) {
                float4 f = pr[j];
                s += f.x + f.y + f.z + f.w;
            }
            inv[t] = 1.0f / s;
        }
        __syncthreads();
    }

    f32x4 acc[4][4];
    #pragma unroll
    for (int m = 0; m < 4; ++m)
        #pragma unroll
        for (int n = 0; n < 4; ++n) acc[m][n] = (f32x4){0.f, 0.f, 0.f, 0.f};

    // stage one full K-tile (A+B, 8 gload_lds per thread, FIFO order fixed)
    auto stage = [&](int b, int k0) {
        #pragma unroll
        for (int l = 0; l < 4; ++l) {
            const int idx = l * 256 + t;
            const int row = idx >> 3;
            const int c   = idx & 7;
            const int gc  = c ^ (row & 7);   // inverse-swizzled source chunk
            gload_lds16(A + (size_t)(m0 + row) * K + k0 + gc * 8, &lds[b][0][idx * 8]);
            gload_lds16(B + (size_t)(n0 + row) * K + k0 + gc * 8, &lds[b][1][idx * 8]);
        }
    };

    const int NT = K >> 6;

    // prologue: tiles 0 and 1 in flight (16 loads/thread outstanding)
    stage(0, 0);
    stage(1, 64);

    for (int tt = 0; tt < NT; ++tt) {
        const int cur = tt & 1;
        // counted wait: tile tt resident (its 8 loads are the oldest)
        if (tt == NT - 1) asm volatile("s_waitcnt vmcnt(0)" ::: "memory");
        else              asm volatile("s_waitcnt vmcnt(8)" ::: "memory");
        __builtin_amdgcn_s_barrier();

        // read ALL fragments for both kk halves
        bf16x8v af[2][4], bfr[2][4];
        #pragma unroll
        for (int kk = 0; kk < 2; ++kk) {
            #pragma unroll
            for (int m = 0; m < 4; ++m) {
                const int row = wr * 64 + m * 16 + rl;
                const int ch  = (kk * 4 + lg) ^ (row & 7);
                af[kk][m] = *(const bf16x8v*)&lds[cur][0][row * 64 + ch * 8];
            }
            #pragma unroll
            for (int n = 0; n < 4; ++n) {
                const int row = wc * 64 + n * 16 + rl;
                const int ch  = (kk * 4 + lg) ^ (row & 7);
                bfr[kk][n] = *(const bf16x8v*)&lds[cur][1][row * 64 + ch * 8];
            }
        }
        asm volatile("s_waitcnt lgkmcnt(0)" ::: "memory");
        __builtin_amdgcn_sched_barrier(0);
        __builtin_amdgcn_s_barrier();   // all waves' reads of buf[cur] retired

        // refill the just-freed buffer; loads stay in flight across barriers
        if (tt + 2 < NT) stage(cur, (tt + 2) * 64);

        #pragma unroll
        for (int kk = 0; kk < 2; ++kk)
            #pragma unroll
            for (int m = 0; m < 4; ++m)
                #pragma unroll
                for (int n = 0; n < 4; ++n)
                    acc[m][n] = __builtin_amdgcn_mfma_f32_16x16x32_bf16(
                        af[kk][m], bfr[kk][n], acc[m][n], 0, 0, 0);
    }

    // epilogue: C/D map col=lane&15, row=(lane>>4)*4+reg (m89-verified)
    const int cif = rl;
    const int rif = lg << 2;
    bf16* T = &lds[0][0][0];   // drained staging LDS: 128*132 bf16 scratch

    if constexpr (V == 1) {
        const float sc2 = scale * 1.4426950408889634f;
        const float sh2 = -8.656170245333781f;   // -6 * log2(e)
        float rs[4][4];   // [m][r] partial row sums over this lane's cols
        #pragma unroll
        for (int m = 0; m < 4; ++m)
            #pragma unroll
            for (int r = 0; r < 4; ++r) rs[m][r] = 0.f;

        #pragma unroll
        for (int m = 0; m < 4; ++m) {
            const int gm = m0 + wr * 64 + m * 16 + rif;
            #pragma unroll
            for (int n = 0; n < 4; ++n) {
                const int col = n0 + wc * 64 + n * 16 + cif;
                #pragma unroll
                for (int r = 0; r < 4; ++r) {
                    const float e = exp2f(fmaf(acc[m][n][r], sc2, sh2));
                    rs[m][r] += e;
                    C[(size_t)(gm + r) * N + col] = (OutT)e;
                }
            }
        }
        // reduce over the 16 rl-lanes (same rows, different cols)
        #pragma unroll
        for (int m = 0; m < 4; ++m)
            #pragma unroll
            for (int r = 0; r < 4; ++r) {
                #pragma unroll
                for (int msk = 1; msk < 16; msk <<= 1)
                    rs[m][r] += __shfl_xor(rs[m][r], msk);
            }
        if ((lane & 15) == 0) {
            const int slot = bx * 2 + wc;
            #pragma unroll
            for (int m = 0; m < 4; ++m) {
                const int gm = m0 + wr * 64 + m * 16 + rif;
                #pragma unroll
                for (int r = 0; r < 4; ++r)
                    pRow[(size_t)(gm + r) * 32 + slot] = rs[m][r];
            }
        }
    } else if constexpr (V == 0) {
        if (n0 >= 2048) {
            // v-region block: transpose T[dl][sl] -> vT coalesced
            #pragma unroll
            for (int m = 0; m < 4; ++m) {
                const int sl = wr * 64 + m * 16 + rif;   // s_local (r contiguous)
                #pragma unroll
                for (int n = 0; n < 4; ++n) {
                    const int dl = wc * 64 + n * 16 + cif;  // d_local
                    const float bb = bias[n0 + dl];
                    bf16x4v pk;
                    #pragma unroll
                    for (int r = 0; r < 4; ++r) pk[r] = (bf16)(acc[m][n][r] + bb);
                    *(bf16x4v*)&T[dl * 132 + sl] = pk;
                }
            }
            __syncthreads();
            const int d  = t >> 1;
            const int sh = (t & 1) << 6;
            const int batch = m0 >> 11;
            const int dg = n0 - 2048 + d;
            const int sg = (m0 & 2047) + sh;
            uint4* dst = (uint4*)&vT[((size_t)batch << 21) + ((size_t)dg << 11) + sg];
            const uint2* srcp = (const uint2*)&T[d * 132 + sh];
            #pragma unroll
            for (int j = 0; j < 8; ++j) {
                uint2 a = srcp[2 * j], b2 = srcp[2 * j + 1];
                dst[j] = (uint4){a.x, a.y, b2.x, b2.y};
            }
        } else {
            // q/k block: gather T[sl][dl] -> 8x16B coalesced stores
            #pragma unroll
            for (int m = 0; m < 4; ++m) {
                const int sl = wr * 64 + m * 16 + rif;
                #pragma unroll
                for (int n = 0; n < 4; ++n) {
                    const int dl = wc * 64 + n * 16 + cif;
                    const float bb = bias[n0 + dl];
                    #pragma unroll
                    for (int r = 0; r < 4; ++r)
                        T[(sl + r) * 132 + dl] = (bf16)(acc[m][n][r] + bb);
                }
            }
            __syncthreads();
            const int s  = t >> 1;
            const int hh = (t & 1) << 6;
            bf16* dst = (n0 < 1024 ? (bf16*)C : (bf16*)C + NX)
                        + (size_t)(m0 + s) * 1024 + (n0 & 1023) + hh;
            const uint2* srcp = (const uint2*)&T[s * 132 + hh];
            #pragma unroll
            for (int j = 0; j < 8; ++j) {
                uint2 a = srcp[2 * j], b2 = srcp[2 * j + 1];
                ((uint4*)dst)[j] = (uint4){a.x, a.y, b2.x, b2.y};
            }
        }
    } else {  // V == 2: normalize by row sum; f32 stores are full 64B runs
        #pragma unroll
        for (int m = 0; m < 4; ++m) {
            const int gm = m0 + wr * 64 + m * 16 + rif;
            const int rloc = wr * 64 + m * 16 + rif;
            #pragma unroll
            for (int n = 0; n < 4; ++n) {
                const int col = n0 + wc * 64 + n * 16 + cif;
                #pragma unroll
                for (int r = 0; r < 4; ++r)
                    C[(size_t)(gm + r) * N + col] = (OutT)(acc[m][n][r] * inv[rloc + r]);
            }
        }
    }
}

// ---------------------------------------------------------------------------
extern "C" void kernel_launch(void* const* d_in, const int* in_sizes, int n_in,
                              void* d_out, int out_size, void* d_ws, size_t ws_size,
                              hipStream_t stream)
{
    const float* x1 = (const float*)d_in[0];
    const float* Wq = (const float*)d_in[1];
    const float* bq = (const float*)d_in[2];
    const float* Wk = (const float*)d_in[3];
    const float* bk = (const float*)d_in[4];
    const float* Wv = (const float*)d_in[5];
    const float* bv = (const float*)d_in[6];
    float* out = (float*)d_out;

    // workspace layout (bf16 elements unless noted)
    bf16* xb     = (bf16*)d_ws;             // x bf16; reused as pRow after QKV
    bf16* wb     = xb + NX;                 // 3*1048576 (Wq,Wk,Wv rows x 1024)
    bf16* qkb    = wb + 3 * NW;             // 2*8388608 (q then k)
    bf16* vTb    = qkb + 2 * (size_t)NX;    // 8388608 (V^T per batch [D][S])
    bf16* scores = vTb + NX;                // 4*2048*2048 (P~)
    float* biases = (float*)(scores + 4 * (size_t)SB * SB); // 3072 f32
    float* partial = (float*)xb;            // [4][2048][32] f32 (xb dead post-QKV)

    // 1. convert inputs to bf16
    convert_kernel<<<dim3(2048), dim3(256), 0, stream>>>(
        x1, Wq, Wk, Wv, bq, bk, bv, xb, wb, biases);

    // 2. fused QKV projection: M=8192, N=3072 (q|k|vT), K=1024; GRP=8 keeps
    //    per-XCD working set inside L2
    gemm_bt<0, bf16><<<dim3(24, 64, 1), dim3(256), 0, stream>>>(
        xb, wb, qkb, vTb, biases, nullptr, 1024, 1024, 8, 0L, 0L, 0L, 1.0f);

    // 3. P~ = exp(QK^T/32 - 6) per batch + partial row sums: M=N=2048, K=1024
    gemm_bt<1, bf16><<<dim3(16, 16, 4), dim3(256), 0, stream>>>(
        qkb, qkb + NX, scores, nullptr, nullptr, partial, SB, DD, 16,
        (long)(SB * DD), (long)(SB * DD), (long)(SB * SB), 1.0f / 32.0f);

    // 4. out = (P~ V) / rowsum per batch: M=2048, N=1024, K=2048, f32 out
    gemm_bt<2, float><<<dim3(8, 16, 4), dim3(256), 0, stream>>>(
        scores, vTb, out, nullptr, nullptr, partial, DD, SB, 8,
        (long)(SB * SB), (long)(SB * DD), (long)(SB * DD), 1.0f);
}

// Round 17
// 155.989 us; speedup vs baseline: 1.1744x; 1.0342x over previous
//
#include <hip/hip_runtime.h>
#include <cstdint>
#include <cstddef>

using bf16 = __bf16;
typedef float f32x4 __attribute__((ext_vector_type(4)));
typedef __bf16 bf16x8v __attribute__((ext_vector_type(8)));
typedef __bf16 bf16x4v __attribute__((ext_vector_type(4)));

// Problem constants: B=4, S=2048, D=1024
#define NX   8388608      // 4*2048*1024
#define NW   1048576      // 1024*1024
#define SB   2048
#define DD   1024

__device__ __forceinline__ void gload_lds16(const bf16* g, bf16* l) {
    __builtin_amdgcn_global_load_lds(
        (const __attribute__((address_space(1))) void*)(g),
        (__attribute__((address_space(3))) void*)(l), 16, 0, 0);
}

// ---------------------------------------------------------------------------
// Convert fp32 inputs -> bf16 in workspace; copy biases (fp32) contiguous.
// ---------------------------------------------------------------------------
__global__ __launch_bounds__(256)
void convert_kernel(const float* __restrict__ x1,
                    const float* __restrict__ Wq, const float* __restrict__ Wk,
                    const float* __restrict__ Wv,
                    const float* __restrict__ bq, const float* __restrict__ bk,
                    const float* __restrict__ bv,
                    bf16* __restrict__ xb, bf16* __restrict__ wb,
                    float* __restrict__ biases)
{
    const int NX4 = NX / 4;
    const int NW4 = NW / 4;
    const int NMAT = NX4 + 3 * NW4;
    const int total = NMAT + 768;
    for (int i = blockIdx.x * 256 + threadIdx.x; i < total; i += gridDim.x * 256) {
        if (i < NMAT) {
            const float* src; bf16* dst; int j;
            if (i < NX4) { src = x1; dst = xb; j = i; }
            else {
                int w = (i - NX4) / NW4;
                j = (i - NX4) - w * NW4;
                src = (w == 0) ? Wq : (w == 1) ? Wk : Wv;
                dst = wb + (size_t)w * NW;
            }
            float4 f = ((const float4*)src)[j];
            bf16x4v o;
            o[0] = (bf16)f.x; o[1] = (bf16)f.y; o[2] = (bf16)f.z; o[3] = (bf16)f.w;
            ((bf16x4v*)dst)[j] = o;
        } else {
            int j = i - NMAT;
            const float* src = (j < 256) ? bq : (j < 512) ? bk : bv;
            ((float4*)biases)[j] = ((const float4*)src)[j & 255];
        }
    }
}

// ---------------------------------------------------------------------------
// Double-buffered counted-vmcnt 128x128 GEMM (round-13 champion, verbatim).
// Per K-tile: vmcnt(8) -> barrier -> 16 ds_read -> lgkmcnt(0)+sched_bar ->
// barrier -> stage(t+2) into freed buffer (loads cross barriers) -> 32 MFMA.
// Tail: vmcnt(0) at t=NT-1.
// C[m][n] = scale * sum_k A[m][k]*B[n][k] (+ epilogue routing)
// A: M x K, B: N x K row-major bf16. 4 waves (2x2 of 64x64), 16x16x32 MFMA.
// Conflict-free XOR swizzle (chunk ^= row&7); T1 XCD block swizzle + GRP
// bx-grouping (L2 working-set control; GRP==gridDim.x -> plain order).
// Epilogue policy (rounds 15/16 lesson): LDS-coalesce ONLY true scatter
// (v-transpose 8B@4KB); direct-store everything else (wave-interleaved runs
// already fill sectors).
// V=0: fused QKV. q/k blocks write direct; v blocks (n0>=2048) transpose
//      through dead staging LDS -> vT [b][d][s], 128B/thread.
// V=1: scores: P~ = exp2(acc*scale*log2e - 6*log2e) bf16 direct + register
//      rowsum -> pRow[row*32 + bx*2 + wc] (deterministic, no atomics).
// V=2: PV: f32 out scaled by 1/rowsum (reduced from pRow at block entry).
// ---------------------------------------------------------------------------
template<int V, typename OutT>
__global__ __launch_bounds__(256)
void gemm_bt(const bf16* __restrict__ A, const bf16* __restrict__ B,
             OutT* __restrict__ C, bf16* __restrict__ vT,
             const float* __restrict__ bias, float* __restrict__ pRow,
             int N, int K, int GRP,
             long sAz, long sBz, long sCz, float scale)
{
    __shared__ bf16 lds[2][2][8192];   // [buf][A|B][128*64] = 64 KiB
    __shared__ float inv[128];         // V==2 only
    const int z = blockIdx.z;
    A += (size_t)z * sAz;
    B += (size_t)z * sBz;
    C += (size_t)z * sCz;
    if constexpr (V == 1 || V == 2) pRow += (size_t)z * (SB * 32);

    // T1: XCD-aware bijective swizzle of the flattened 2D grid
    const int gx = gridDim.x;
    const int gy = gridDim.y;
    const int nwg = gx * gy;
    const int orig = (int)blockIdx.y * gx + (int)blockIdx.x;
    const int q8 = nwg >> 3;
    const int tile = (orig & 7) * q8 + (orig >> 3);
    // bx-grouped ordering: (bx-group, by, bx-in-group); GRP==gx -> plain
    const int gsz = GRP * gy;
    const int bxg = tile / gsz;
    const int rem = tile - bxg * gsz;
    const int by  = rem / GRP;
    const int bx  = bxg * GRP + (rem - (rem / GRP) * GRP);

    const int n0 = bx * 128;
    const int m0 = by * 128;
    const int t = threadIdx.x;
    const int lane = t & 63;
    const int wid = t >> 6;
    const int wr = wid >> 1, wc = wid & 1;
    const int rl = lane & 15, lg = lane >> 4;

    if constexpr (V == 2) {
        if (t < 128) {
            const float4* pr = (const float4*)&pRow[(size_t)(m0 + t) * 32];
            float s = 0.f;
            #pragma unroll
            for (int j = 0; j < 8; ++j) {
                float4 f = pr[j];
                s += f.x + f.y + f.z + f.w;
            }
            inv[t] = 1.0f / s;
        }
        __syncthreads();
    }

    f32x4 acc[4][4];
    #pragma unroll
    for (int m = 0; m < 4; ++m)
        #pragma unroll
        for (int n = 0; n < 4; ++n) acc[m][n] = (f32x4){0.f, 0.f, 0.f, 0.f};

    // stage one full K-tile (A+B, 8 gload_lds per thread, FIFO order fixed)
    auto stage = [&](int b, int k0) {
        #pragma unroll
        for (int l = 0; l < 4; ++l) {
            const int idx = l * 256 + t;
            const int row = idx >> 3;
            const int c   = idx & 7;
            const int gc  = c ^ (row & 7);   // inverse-swizzled source chunk
            gload_lds16(A + (size_t)(m0 + row) * K + k0 + gc * 8, &lds[b][0][idx * 8]);
            gload_lds16(B + (size_t)(n0 + row) * K + k0 + gc * 8, &lds[b][1][idx * 8]);
        }
    };

    const int NT = K >> 6;

    // prologue: tiles 0 and 1 in flight (16 loads/thread outstanding)
    stage(0, 0);
    stage(1, 64);

    for (int tt = 0; tt < NT; ++tt) {
        const int cur = tt & 1;
        // counted wait: tile tt resident (its 8 loads are the oldest)
        if (tt == NT - 1) asm volatile("s_waitcnt vmcnt(0)" ::: "memory");
        else              asm volatile("s_waitcnt vmcnt(8)" ::: "memory");
        __builtin_amdgcn_s_barrier();

        // read ALL fragments for both kk halves
        bf16x8v af[2][4], bfr[2][4];
        #pragma unroll
        for (int kk = 0; kk < 2; ++kk) {
            #pragma unroll
            for (int m = 0; m < 4; ++m) {
                const int row = wr * 64 + m * 16 + rl;
                const int ch  = (kk * 4 + lg) ^ (row & 7);
                af[kk][m] = *(const bf16x8v*)&lds[cur][0][row * 64 + ch * 8];
            }
            #pragma unroll
            for (int n = 0; n < 4; ++n) {
                const int row = wc * 64 + n * 16 + rl;
                const int ch  = (kk * 4 + lg) ^ (row & 7);
                bfr[kk][n] = *(const bf16x8v*)&lds[cur][1][row * 64 + ch * 8];
            }
        }
        asm volatile("s_waitcnt lgkmcnt(0)" ::: "memory");
        __builtin_amdgcn_sched_barrier(0);
        __builtin_amdgcn_s_barrier();   // all waves' reads of buf[cur] retired

        // refill the just-freed buffer; loads stay in flight across barriers
        if (tt + 2 < NT) stage(cur, (tt + 2) * 64);

        #pragma unroll
        for (int kk = 0; kk < 2; ++kk)
            #pragma unroll
            for (int m = 0; m < 4; ++m)
                #pragma unroll
                for (int n = 0; n < 4; ++n)
                    acc[m][n] = __builtin_amdgcn_mfma_f32_16x16x32_bf16(
                        af[kk][m], bfr[kk][n], acc[m][n], 0, 0, 0);
    }

    // epilogue: C/D map col=lane&15, row=(lane>>4)*4+reg (m89-verified)
    const int cif = rl;
    const int rif = lg << 2;
    bf16* T = &lds[0][0][0];   // drained staging LDS: 128*132 bf16 scratch

    if constexpr (V == 1) {
        const float sc2 = scale * 1.4426950408889634f;
        const float sh2 = -8.656170245333781f;   // -6 * log2(e)
        float rs[4][4];   // [m][r] partial row sums over this lane's cols
        #pragma unroll
        for (int m = 0; m < 4; ++m)
            #pragma unroll
            for (int r = 0; r < 4; ++r) rs[m][r] = 0.f;

        #pragma unroll
        for (int m = 0; m < 4; ++m) {
            const int gm = m0 + wr * 64 + m * 16 + rif;
            #pragma unroll
            for (int n = 0; n < 4; ++n) {
                const int col = n0 + wc * 64 + n * 16 + cif;
                #pragma unroll
                for (int r = 0; r < 4; ++r) {
                    const float e = exp2f(fmaf(acc[m][n][r], sc2, sh2));
                    rs[m][r] += e;
                    C[(size_t)(gm + r) * N + col] = (OutT)e;
                }
            }
        }
        // reduce over the 16 rl-lanes (same rows, different cols)
        #pragma unroll
        for (int m = 0; m < 4; ++m)
            #pragma unroll
            for (int r = 0; r < 4; ++r) {
                #pragma unroll
                for (int msk = 1; msk < 16; msk <<= 1)
                    rs[m][r] += __shfl_xor(rs[m][r], msk);
            }
        if ((lane & 15) == 0) {
            const int slot = bx * 2 + wc;
            #pragma unroll
            for (int m = 0; m < 4; ++m) {
                const int gm = m0 + wr * 64 + m * 16 + rif;
                #pragma unroll
                for (int r = 0; r < 4; ++r)
                    pRow[(size_t)(gm + r) * 32 + slot] = rs[m][r];
            }
        }
    } else if constexpr (V == 0) {
        if (n0 >= 2048) {
            // v-region block: transpose via dead staging LDS, coalesced write.
            #pragma unroll
            for (int m = 0; m < 4; ++m) {
                const int sl = wr * 64 + m * 16 + rif;   // s_local (r contiguous)
                #pragma unroll
                for (int n = 0; n < 4; ++n) {
                    const int dl = wc * 64 + n * 16 + cif;  // d_local
                    const float bb = bias[n0 + dl];
                    bf16x4v pk;
                    #pragma unroll
                    for (int r = 0; r < 4; ++r) pk[r] = (bf16)(acc[m][n][r] + bb);
                    *(bf16x4v*)&T[dl * 132 + sl] = pk;
                }
            }
            __syncthreads();
            // thread -> (d = t>>1, s-half = (t&1)*64): 64 contig bf16 = 128B
            const int d  = t >> 1;
            const int sh = (t & 1) << 6;
            const int batch = m0 >> 11;
            const int dg = n0 - 2048 + d;
            const int sg = (m0 & 2047) + sh;
            uint4* dst = (uint4*)&vT[((size_t)batch << 21) + ((size_t)dg << 11) + sg];
            const uint2* srcp = (const uint2*)&T[d * 132 + sh];
            #pragma unroll
            for (int j = 0; j < 8; ++j) {
                uint2 a = srcp[2 * j], b2 = srcp[2 * j + 1];
                dst[j] = (uint4){a.x, a.y, b2.x, b2.y};
            }
        } else {
            // q/k block: direct stores (wave-interleaved runs fill sectors)
            #pragma unroll
            for (int m = 0; m < 4; ++m) {
                const int gm = m0 + wr * 64 + m * 16 + rif;
                #pragma unroll
                for (int n = 0; n < 4; ++n) {
                    const int col = n0 + wc * 64 + n * 16 + cif;
                    const float bb = bias[col];
                    if (col < 1024) {
                        #pragma unroll
                        for (int r = 0; r < 4; ++r)
                            C[(size_t)(gm + r) * 1024 + col] = (OutT)(acc[m][n][r] + bb);
                    } else {
                        #pragma unroll
                        for (int r = 0; r < 4; ++r)
                            C[NX + (size_t)(gm + r) * 1024 + (col - 1024)] = (OutT)(acc[m][n][r] + bb);
                    }
                }
            }
        }
    } else {  // V == 2: normalize by row sum; f32 stores are full 64B runs
        #pragma unroll
        for (int m = 0; m < 4; ++m) {
            const int gm = m0 + wr * 64 + m * 16 + rif;
            const int rloc = wr * 64 + m * 16 + rif;
            #pragma unroll
            for (int n = 0; n < 4; ++n) {
                const int col = n0 + wc * 64 + n * 16 + cif;
                #pragma unroll
                for (int r = 0; r < 4; ++r)
                    C[(size_t)(gm + r) * N + col] = (OutT)(acc[m][n][r] * inv[rloc + r]);
            }
        }
    }
}

// ---------------------------------------------------------------------------
extern "C" void kernel_launch(void* const* d_in, const int* in_sizes, int n_in,
                              void* d_out, int out_size, void* d_ws, size_t ws_size,
                              hipStream_t stream)
{
    const float* x1 = (const float*)d_in[0];
    const float* Wq = (const float*)d_in[1];
    const float* bq = (const float*)d_in[2];
    const float* Wk = (const float*)d_in[3];
    const float* bk = (const float*)d_in[4];
    const float* Wv = (const float*)d_in[5];
    const float* bv = (const float*)d_in[6];
    float* out = (float*)d_out;

    // workspace layout (bf16 elements unless noted)
    bf16* xb     = (bf16*)d_ws;             // x bf16; reused as pRow after QKV
    bf16* wb     = xb + NX;                 // 3*1048576 (Wq,Wk,Wv rows x 1024)
    bf16* qkb    = wb + 3 * NW;             // 2*8388608 (q then k)
    bf16* vTb    = qkb + 2 * (size_t)NX;    // 8388608 (V^T per batch [D][S])
    bf16* scores = vTb + NX;                // 4*2048*2048 (P~)
    float* biases = (float*)(scores + 4 * (size_t)SB * SB); // 3072 f32
    float* partial = (float*)xb;            // [4][2048][32] f32 (xb dead post-QKV)

    // 1. convert inputs to bf16
    convert_kernel<<<dim3(2048), dim3(256), 0, stream>>>(
        x1, Wq, Wk, Wv, bq, bk, bv, xb, wb, biases);

    // 2. fused QKV projection: M=8192, N=3072 (q|k|vT), K=1024; GRP=8 keeps
    //    per-XCD working set inside L2
    gemm_bt<0, bf16><<<dim3(24, 64, 1), dim3(256), 0, stream>>>(
        xb, wb, qkb, vTb, biases, nullptr, 1024, 1024, 8, 0L, 0L, 0L, 1.0f);

    // 3. P~ = exp(QK^T/32 - 6) per batch + partial row sums: M=N=2048, K=1024
    gemm_bt<1, bf16><<<dim3(16, 16, 4), dim3(256), 0, stream>>>(
        qkb, qkb + NX, scores, nullptr, nullptr, partial, SB, DD, 16,
        (long)(SB * DD), (long)(SB * DD), (long)(SB * SB), 1.0f / 32.0f);

    // 4. out = (P~ V) / rowsum per batch: M=2048, N=1024, K=2048, f32 out
    gemm_bt<2, float><<<dim3(8, 16, 4), dim3(256), 0, stream>>>(
        scores, vTb, out, nullptr, nullptr, partial, DD, SB, 8,
        (long)(SB * SB), (long)(SB * DD), (long)(SB * DD), 1.0f);
}